// Round 4
// baseline (577.269 us; speedup 1.0000x reference)
//
#include <hip/hip_runtime.h>

// ---------------- common helpers ----------------

typedef __attribute__((ext_vector_type(8))) short s16x8;    // 8 x bf16 (4 VGPRs)
typedef __attribute__((ext_vector_type(16))) float f32x16;  // 32x32 MFMA accumulator

__device__ __forceinline__ unsigned short f2bf(float f) {
  union { float f; unsigned u; } v; v.f = f;
  unsigned r = v.u + 0x7fffu + ((v.u >> 16) & 1u);   // round-to-nearest-even
  return (unsigned short)(r >> 16);
}
__device__ __forceinline__ float bf2f(unsigned short h) {
  union { unsigned u; float f; } v; v.u = ((unsigned)h) << 16; return v.f;
}
__device__ __forceinline__ void gload_lds16(const void* g, void* l) {
  __builtin_amdgcn_global_load_lds(
      (const __attribute__((address_space(1))) void*)g,
      (__attribute__((address_space(3))) void*)l, 16, 0, 0);
}

// ---------------- fp32 -> bf16 convert (weights) ----------------

__global__ void conv_bf16(const float4* __restrict__ src, ushort4* __restrict__ dst, int n4) {
  int i = blockIdx.x * blockDim.x + threadIdx.x;
  if (i >= n4) return;
  float4 v = src[i];
  ushort4 o;
  o.x = f2bf(v.x); o.y = f2bf(v.y); o.z = f2bf(v.z); o.w = f2bf(v.w);
  dst[i] = o;
}

// ---------------- fused time-shift mix -> xk, xv, xr (bf16) ----------------

__global__ void prep_mix3(const float4* __restrict__ hidden,
                          const float4* __restrict__ tmk,
                          const float4* __restrict__ tmv,
                          const float4* __restrict__ tmr,
                          ushort4* __restrict__ xk, ushort4* __restrict__ xv,
                          ushort4* __restrict__ xr,
                          int S, int H4, long long total4) {
  long long i = (long long)blockIdx.x * blockDim.x + threadIdx.x;
  if (i >= total4) return;
  int h4 = (int)(i % H4);
  long long sb = i / H4;          // b*S + s
  int s = (int)(sb % S);
  float4 cur = hidden[i];
  float4 prev = make_float4(0.f, 0.f, 0.f, 0.f);
  if (s > 0) prev = hidden[i - H4];
  float4 mk = tmk[h4], mv = tmv[h4], mr = tmr[h4];
  ushort4 ok, ov, orr;
  ok.x = f2bf(cur.x * mk.x + prev.x * (1.f - mk.x));
  ok.y = f2bf(cur.y * mk.y + prev.y * (1.f - mk.y));
  ok.z = f2bf(cur.z * mk.z + prev.z * (1.f - mk.z));
  ok.w = f2bf(cur.w * mk.w + prev.w * (1.f - mk.w));
  ov.x = f2bf(cur.x * mv.x + prev.x * (1.f - mv.x));
  ov.y = f2bf(cur.y * mv.y + prev.y * (1.f - mv.y));
  ov.z = f2bf(cur.z * mv.z + prev.z * (1.f - mv.z));
  ov.w = f2bf(cur.w * mv.w + prev.w * (1.f - mv.w));
  orr.x = f2bf(cur.x * mr.x + prev.x * (1.f - mr.x));
  orr.y = f2bf(cur.y * mr.y + prev.y * (1.f - mr.y));
  orr.z = f2bf(cur.z * mr.z + prev.z * (1.f - mr.z));
  orr.w = f2bf(cur.w * mr.w + prev.w * (1.f - mr.w));
  xk[i] = ok; xv[i] = ov; xr[i] = orr;
}

// ---------------- bf16 NT GEMM: C[M,N] = A[M,K] * B[N,K]^T ----------------
// 256x256 tile, NEW BK=64 (128-B LDS rows), 8 waves (2M x 4N, per-wave 128x64
// via 4x2 of 32x32x16 MFMA). Why BK=64: with 64-B rows every ds_read_b128 ran
// at 12 cyc (exactly 4 conflict cyc each, SQ_LDS_BANK_CONFLICT 6.29M,
// schedule-independent r1-r3); all conflict-free measured patterns (m201,
// m214 attn) use >=128-B rows. Swizzle is the m214-verified class:
// chunk16 ^= (row & 7) (full 8-slot spread per 8 rows, 32-row frag footprint,
// same 32x32x16 frags as m214's K_lds).
// LDS: A ring-3 (3 x 32 KiB, staged 2 tiles ahead) + B ring-2 (2 x 32 KiB,
// staged 1 ahead) = 160 KiB. One counted vmcnt(4) per iter (tail: 0), 2
// barriers per 64-K step. Register pipeline: every MFMA cluster's fragments
// were ds_read-issued >= half an iteration earlier.
//   phase A: STAGE_A(t+2) | STAGE_B(t+1) | read a23(t)
//            | cluster1: acc[0..1] += a01(t) x bfr(t)
//            | vmcnt(4) [A(t+1),B(t+1) landed; A(t+2) in flight] | BARRIER-1
//   phase B: read a01(t+1) | cluster2: acc[2..3] += a23(t) x bfr(t)
//            | read bfr(t+1) (after last bfr use; WAR-at-issue, r3-proven)
//            | BARRIER-2
// WAR safety: STAGE_A(t+2) writes A-slot (t+2)%3 = (t-1)%3; all reads of
// A(t-1) (a23 at t-1.A, a01 at t-2.B) complete before their consuming
// clusters, hence before BARRIER-2(t-1) < the stage. STAGE_B(t+1) writes
// B-slot (t-1)&1; bfr(t-1) reads (t-2.B) complete before cluster1(t-1) <
// BARRIER-1(t-1) < the stage. vmcnt(4) at BARRIER-1(t): younger ops = exactly
// A(t+2)'s 4 loads -> A(t+1)+B(t+1) landed before phase-B reads them.
// EPI: 0 = fp32; 1 = sigmoid bf16; 2 = bf16.

template <int EPI>
__global__ __launch_bounds__(512, 2) void gemm_bt(
    const unsigned short* __restrict__ A, const unsigned short* __restrict__ B,
    float* __restrict__ Cf, unsigned short* __restrict__ Cb,
    int M, int N, int K) {
  __shared__ unsigned short ldsA[3 * 16384];  // 3 x 32 KiB A-tile ring
  __shared__ unsigned short ldsB[2 * 16384];  // 2 x 32 KiB B-tile ring

  const int tid = threadIdx.x;
  const int wave = tid >> 6;
  const int lane = tid & 63;

  // XCD-aware bijective block swizzle: nwg % 8 == 0 (256 blocks). All 32
  // blocks of one XCD share a single 1-MiB B panel (L2-resident).
  const int nwg = (int)gridDim.x;
  const int q = nwg >> 3;
  const int wg = (blockIdx.x & 7) * q + (blockIdx.x >> 3);
  const int GM = M >> 8;
  const int bm = (wg % GM) * 256;
  const int bn = (wg / GM) * 256;

  const int wm = (wave >> 2) * 128;    // wave's 128x64 sub-tile
  const int wn = (wave & 3) * 64;
  const int lrow = lane & 31;
  const int lq = lane >> 5;            // k-half selector within a 16-k step

  f32x16 acc[4][2] = {};

  // ---- staging (per tile: 4 rounds of 64 rows x 128 B per matrix) ----
  // round r, thread t: row = r*64 + (t>>3), dest chunk16 = t&7 (LDS linear:
  // wave-uniform base + lane*16). Inverse swizzle on the GLOBAL source:
  // src col16 = (t&7) ^ (row&7), row&7 == (t>>3)&7 for all rounds.
  const int srow = tid >> 3;
  const int scol = ((tid & 7) ^ (srow & 7)) * 8;
  const unsigned short* gA = A + (long long)(bm + srow) * K + scol;
  const unsigned short* gB = B + (long long)(bn + srow) * K + scol;
  const int rstep = K << 6;            // 64*K shorts = one 64-row round

#define STAGE_A(slot)                                                \
  {                                                                  \
    unsigned short* d = ldsA + (slot) * 16384 + wave * 512;          \
    gload_lds16(gA, d);                                              \
    gload_lds16(gA + rstep, d + 4096);                               \
    gload_lds16(gA + 2 * rstep, d + 8192);                           \
    gload_lds16(gA + 3 * rstep, d + 12288);                          \
    gA += 64;                                                        \
  }
#define STAGE_B(slot)                                                \
  {                                                                  \
    unsigned short* d = ldsB + (slot) * 16384 + wave * 512;          \
    gload_lds16(gB, d);                                              \
    gload_lds16(gB + rstep, d + 4096);                               \
    gload_lds16(gB + 2 * rstep, d + 8192);                           \
    gload_lds16(gB + 3 * rstep, d + 12288);                          \
    gB += 64;                                                        \
  }

  // ---- fragment read bases (shorts within a 16384-short slot) ----
  // row R, k-step ks: col16 = 2*ks+lq, swizzled chunk = col16 ^ (R&7);
  // R&7 == lane&7 for every frag row (wm, mt*32, wn multiples of 8).
  int sA[4], sB[4];
#pragma unroll
  for (int ks = 0; ks < 4; ++ks) {
    int c = (((2 * ks + lq) ^ (lane & 7)) * 8);
    sA[ks] = (wm + lrow) * 64 + c;
    sB[ks] = (wn + lrow) * 64 + c;
  }

  const int NT = K >> 6;   // K/64 (= 32 here; >= 3 required)

  s16x8 a01[2][4], a23[2][4], bfr[2][4];   // single-buffered fragments

  // A slots for tiles t, t+1, t+2; B slot of tile t
  int aS0 = 0, aS1 = 1, aS2 = 2, bS = 0;

  // ---- prologue: A(0),B(0),A(1) staged; wait A(0)+B(0); read tile-0 set1
  STAGE_A(0);
  STAGE_B(0);
  STAGE_A(1);
  asm volatile("s_waitcnt vmcnt(4)" ::: "memory");   // A(0),B(0) landed
  __builtin_amdgcn_sched_barrier(0);
  __builtin_amdgcn_s_barrier();
  __builtin_amdgcn_sched_barrier(0);
#pragma unroll
  for (int mt = 0; mt < 2; ++mt)
#pragma unroll
    for (int ks = 0; ks < 4; ++ks)
      a01[mt][ks] = *(const s16x8*)(ldsA + sA[ks] + mt * 2048);
#pragma unroll
  for (int nt = 0; nt < 2; ++nt)
#pragma unroll
    for (int ks = 0; ks < 4; ++ks)
      bfr[nt][ks] = *(const s16x8*)(ldsB + sB[ks] + nt * 2048);

  for (int t = 0; t < NT; ++t) {
    // ======== phase A ========
    if (t + 2 < NT) STAGE_A(aS2);
    if (t + 1 < NT) STAGE_B(bS ^ 1);
    {
      const unsigned short* sa = ldsA + aS0 * 16384;
#pragma unroll
      for (int mt = 0; mt < 2; ++mt)
#pragma unroll
        for (int ks = 0; ks < 4; ++ks)
          a23[mt][ks] = *(const s16x8*)(sa + sA[ks] + (2 + mt) * 2048);
    }
    __builtin_amdgcn_s_setprio(1);
#pragma unroll
    for (int ks = 0; ks < 4; ++ks)
#pragma unroll
      for (int mt = 0; mt < 2; ++mt)
#pragma unroll
        for (int nt = 0; nt < 2; ++nt)
          acc[mt][nt] = __builtin_amdgcn_mfma_f32_32x32x16_bf16(
              a01[mt][ks], bfr[nt][ks], acc[mt][nt], 0, 0, 0);
    __builtin_amdgcn_s_setprio(0);

    if (t + 2 < NT) {
      asm volatile("s_waitcnt vmcnt(4)" ::: "memory");  // A(t+1),B(t+1) landed
    } else if (t + 1 < NT) {
      asm volatile("s_waitcnt vmcnt(0)" ::: "memory");  // drain: last tile
    }
    __builtin_amdgcn_sched_barrier(0);
    __builtin_amdgcn_s_barrier();
    __builtin_amdgcn_sched_barrier(0);

    // ======== phase B ========
    if (t + 1 < NT) {
      const unsigned short* sa = ldsA + aS1 * 16384;
#pragma unroll
      for (int mt = 0; mt < 2; ++mt)
#pragma unroll
        for (int ks = 0; ks < 4; ++ks)
          a01[mt][ks] = *(const s16x8*)(sa + sA[ks] + mt * 2048);
    }
    __builtin_amdgcn_s_setprio(1);
#pragma unroll
    for (int ks = 0; ks < 4; ++ks)
#pragma unroll
      for (int mt = 0; mt < 2; ++mt)
#pragma unroll
        for (int nt = 0; nt < 2; ++nt)
          acc[2 + mt][nt] = __builtin_amdgcn_mfma_f32_32x32x16_bf16(
              a23[mt][ks], bfr[nt][ks], acc[2 + mt][nt], 0, 0, 0);
    __builtin_amdgcn_s_setprio(0);
    if (t + 1 < NT) {
      const unsigned short* sbp = ldsB + (bS ^ 1) * 16384;
#pragma unroll
      for (int nt = 0; nt < 2; ++nt)
#pragma unroll
        for (int ks = 0; ks < 4; ++ks)
          bfr[nt][ks] = *(const s16x8*)(sbp + sB[ks] + nt * 2048);
    }
    __builtin_amdgcn_s_barrier();

    int tmp = aS0; aS0 = aS1; aS1 = aS2; aS2 = tmp;
    bS ^= 1;
  }
#undef STAGE_A
#undef STAGE_B

  // epilogue: 32x32 C/D layout col=lane&31, row=(reg&3)+8*(reg>>2)+4*(lane>>5)
#pragma unroll
  for (int mt = 0; mt < 4; ++mt)
#pragma unroll
    for (int nt = 0; nt < 2; ++nt)
#pragma unroll
      for (int r = 0; r < 16; ++r) {
        int row = bm + wm + mt * 32 + (r & 3) + 8 * (r >> 2) + 4 * lq;
        int col = bn + wn + nt * 32 + lrow;
        float v = acc[mt][nt][r];
        long long idx = (long long)row * N + col;
        if (EPI == 0) {
          Cf[idx] = v;
        } else if (EPI == 1) {
          float s = 1.f / (1.f + __expf(-v));
          Cb[idx] = f2bf(s);
        } else {
          Cb[idx] = f2bf(v);
        }
      }
}

// ---------------- chunked WKV scan (k now bf16) ----------------

#define NEG_INF_F (-1e38f)

__global__ void scan_phase1(const unsigned short* __restrict__ kb,
                            const unsigned short* __restrict__ vb,
                            const float* __restrict__ td,
                            float* __restrict__ locN, float* __restrict__ locD,
                            float* __restrict__ locM,
                            int S, int D, int C, int L) {
  int t = blockIdx.x * blockDim.x + threadIdx.x;  // over B*C*D
  int d = t % D;
  int c = (t / D) % C;
  int b = t / (D * C);
  float w = -__expf(td[d]);
  float num = 0.f, den = 0.f, m = NEG_INF_F;
  long long base = ((long long)(b * S + c * L)) * D + d;
  for (int i = 0; i < L; ++i) {
    float kk = bf2f(kb[base]);
    float vv = bf2f(vb[base]);
    base += D;
    float mn = fmaxf(m + w, kk);
    float e1 = __expf(m + w - mn);
    float e2 = __expf(kk - mn);
    num = e1 * num + e2 * vv;
    den = e1 * den + e2;
    m = mn;
  }
  int o = (b * C + c) * D + d;
  locN[o] = num; locD[o] = den; locM[o] = m;
}

__global__ void scan_phase2(const float* __restrict__ td,
                            const float* __restrict__ locN, const float* __restrict__ locD,
                            const float* __restrict__ locM,
                            float* __restrict__ inN, float* __restrict__ inD,
                            float* __restrict__ inM,
                            int Bc, int D, int C, int L) {
  int t = blockIdx.x * blockDim.x + threadIdx.x;  // over B*D
  if (t >= Bc * D) return;
  int d = t % D, b = t / D;
  float w = -__expf(td[d]);
  float Lw = (float)L * w;
  float num = 0.f, den = 0.f, m = NEG_INF_F;
  for (int c = 0; c < C; ++c) {
    int o = (b * C + c) * D + d;
    inN[o] = num; inD[o] = den; inM[o] = m;
    float sm = m + Lw;                 // decay incoming state over whole chunk
    float lm = locM[o];
    float m2 = fmaxf(sm, lm);
    float e1 = __expf(sm - m2);
    float e2 = __expf(lm - m2);
    num = e1 * num + e2 * locN[o];
    den = e1 * den + e2 * locD[o];
    m = m2;
  }
}

__global__ void scan_phase3(const unsigned short* __restrict__ kb,
                            const unsigned short* __restrict__ vb,
                            const unsigned short* __restrict__ rb,
                            const float* __restrict__ td, const float* __restrict__ tfirst,
                            const float* __restrict__ inN, const float* __restrict__ inD,
                            const float* __restrict__ inM,
                            unsigned short* __restrict__ rr,
                            int S, int D, int C, int L) {
  int t = blockIdx.x * blockDim.x + threadIdx.x;  // over B*C*D
  int d = t % D;
  int c = (t / D) % C;
  int b = t / (D * C);
  float w = -__expf(td[d]);
  float tfd = tfirst[d];
  int o = (b * C + c) * D + d;
  float num = inN[o], den = inD[o], m = inM[o];
  long long base = ((long long)(b * S + c * L)) * D + d;
  for (int i = 0; i < L; ++i) {
    float kk = bf2f(kb[base]);
    float vv = bf2f(vb[base]);
    float rv = bf2f(rb[base]);
    float ktf = kk + tfd;
    float mo = fmaxf(m, ktf);
    float e1 = __expf(m - mo);
    float e2 = __expf(ktf - mo);
    float out = (e1 * num + e2 * vv) / (e1 * den + e2);
    rr[base] = f2bf(out * rv);
    float mn = fmaxf(m + w, kk);
    e1 = __expf(m + w - mn);
    e2 = __expf(kk - mn);
    num = e1 * num + e2 * vv;
    den = e1 * den + e2;
    m = mn;
    base += D;
  }
}

// ---------------- launch ----------------

extern "C" void kernel_launch(void* const* d_in, const int* in_sizes, int n_in,
                              void* d_out, int out_size, void* d_ws, size_t ws_size,
                              hipStream_t stream) {
  const float* hidden = (const float*)d_in[0];
  const float* td  = (const float*)d_in[1];
  const float* tfi = (const float*)d_in[2];
  const float* tmk = (const float*)d_in[3];
  const float* tmv = (const float*)d_in[4];
  const float* tmr = (const float*)d_in[5];
  const float* Wk  = (const float*)d_in[6];
  const float* Wv  = (const float*)d_in[7];
  const float* Wr  = (const float*)d_in[8];
  const float* Wo  = (const float*)d_in[9];
  float* out = (float*)d_out;

  const int H = in_sizes[1];                 // 2048
  const int D = H;
  const long long BS = (long long)in_sizes[0] / H;  // 8192 = B*S
  const int S = 2048;
  const int B = (int)(BS / S);               // 4
  const int C = 32, L = S / C;               // 32 chunks of 64

  // workspace layout (110 MiB, proven safe):
  //   W_b [0,8) | X [8,40) | Y [40,72) | Z [72,104) | states [104,110)
  char* ws = (char*)d_ws;
  const size_t MB = 1u << 20;
  unsigned short* W_b = (unsigned short*)(ws + 0 * MB);
  unsigned short* X   = (unsigned short*)(ws + 8 * MB);
  unsigned short* Y   = (unsigned short*)(ws + 40 * MB);
  unsigned short* Z   = (unsigned short*)(ws + 72 * MB);
  float* locN         = (float*)(ws + 104 * MB);
  float* locD         = (float*)(ws + 105 * MB);
  float* locM         = (float*)(ws + 106 * MB);
  float* inN          = (float*)(ws + 107 * MB);
  float* inD          = (float*)(ws + 108 * MB);
  float* inM          = (float*)(ws + 109 * MB);
  unsigned short* kb  = (unsigned short*)out;   // bf16 k scratch in d_out

  int n4w = H * H / 4;
  int cbk = (n4w + 255) / 256;
  long long total4 = BS * H / 4;
  int pbk = (int)((total4 + 255) / 256);
  int nwg = (int)((BS / 256) * (D / 256));   // 32 * 8 = 256 blocks, 1/CU

  // fused time-shift mix (one pass over hidden)
  prep_mix3<<<pbk, 256, 0, stream>>>((const float4*)hidden,
                                     (const float4*)tmk, (const float4*)tmv, (const float4*)tmr,
                                     (ushort4*)X, (ushort4*)Y, (ushort4*)Z, S, H / 4, total4);

  // k = xk @ Wk^T  (bf16 -> d_out scratch)
  conv_bf16<<<cbk, 256, 0, stream>>>((const float4*)Wk, (ushort4*)W_b, n4w);
  gemm_bt<2><<<nwg, 512, 0, stream>>>(X, W_b, nullptr, kb, (int)BS, D, H);

  // v = xv @ Wv^T  (bf16 -> X)
  conv_bf16<<<cbk, 256, 0, stream>>>((const float4*)Wv, (ushort4*)W_b, n4w);
  gemm_bt<2><<<nwg, 512, 0, stream>>>(Y, W_b, nullptr, X, (int)BS, D, H);

  // r = sigmoid(xr @ Wr^T)  (bf16 -> Y)
  conv_bf16<<<cbk, 256, 0, stream>>>((const float4*)Wr, (ushort4*)W_b, n4w);
  gemm_bt<1><<<nwg, 512, 0, stream>>>(Z, W_b, nullptr, Y, (int)BS, D, H);

  // chunked WKV scan, fused r * rwkv -> Z (bf16)
  int nscan = B * C * D;
  scan_phase1<<<nscan / 256, 256, 0, stream>>>(kb, X, td, locN, locD, locM, S, D, C, L);
  scan_phase2<<<(B * D + 255) / 256, 256, 0, stream>>>(td, locN, locD, locM, inN, inD, inM, B, D, C, L);
  scan_phase3<<<nscan / 256, 256, 0, stream>>>(kb, X, Y, td, tfi, inN, inD, inM, Z, S, D, C, L);

  // out = (r * rwkv) @ Wo^T  (fp32 -> d_out; kb dead now)
  conv_bf16<<<cbk, 256, 0, stream>>>((const float4*)Wo, (ushort4*)W_b, n4w);
  gemm_bt<0><<<nwg, 512, 0, stream>>>(Z, W_b, out, nullptr, (int)BS, H, D);
}

// Round 5
// 544.157 us; speedup vs baseline: 1.0608x; 1.0608x over previous
//
#include <hip/hip_runtime.h>

// ---------------- common helpers ----------------

typedef __attribute__((ext_vector_type(8))) short s16x8;   // 8 x bf16 (4 VGPRs)
typedef __attribute__((ext_vector_type(4))) float f32x4;   // 16x16 MFMA accumulator

__device__ __forceinline__ unsigned short f2bf(float f) {
  union { float f; unsigned u; } v; v.f = f;
  unsigned r = v.u + 0x7fffu + ((v.u >> 16) & 1u);   // round-to-nearest-even
  return (unsigned short)(r >> 16);
}
__device__ __forceinline__ float bf2f(unsigned short h) {
  union { unsigned u; float f; } v; v.u = ((unsigned)h) << 16; return v.f;
}
__device__ __forceinline__ void gload_lds16(const void* g, void* l) {
  __builtin_amdgcn_global_load_lds(
      (const __attribute__((address_space(1))) void*)g,
      (__attribute__((address_space(3))) void*)l, 16, 0, 0);
}

// ---------------- fp32 -> bf16 convert (weights) ----------------

__global__ void conv_bf16(const float4* __restrict__ src, ushort4* __restrict__ dst, int n4) {
  int i = blockIdx.x * blockDim.x + threadIdx.x;
  if (i >= n4) return;
  float4 v = src[i];
  ushort4 o;
  o.x = f2bf(v.x); o.y = f2bf(v.y); o.z = f2bf(v.z); o.w = f2bf(v.w);
  dst[i] = o;
}

// ---------------- fused time-shift mix -> xk, xv, xr (bf16) ----------------

__global__ void prep_mix3(const float4* __restrict__ hidden,
                          const float4* __restrict__ tmk,
                          const float4* __restrict__ tmv,
                          const float4* __restrict__ tmr,
                          ushort4* __restrict__ xk, ushort4* __restrict__ xv,
                          ushort4* __restrict__ xr,
                          int S, int H4, long long total4) {
  long long i = (long long)blockIdx.x * blockDim.x + threadIdx.x;
  if (i >= total4) return;
  int h4 = (int)(i % H4);
  long long sb = i / H4;          // b*S + s
  int s = (int)(sb % S);
  float4 cur = hidden[i];
  float4 prev = make_float4(0.f, 0.f, 0.f, 0.f);
  if (s > 0) prev = hidden[i - H4];
  float4 mk = tmk[h4], mv = tmv[h4], mr = tmr[h4];
  ushort4 ok, ov, orr;
  ok.x = f2bf(cur.x * mk.x + prev.x * (1.f - mk.x));
  ok.y = f2bf(cur.y * mk.y + prev.y * (1.f - mk.y));
  ok.z = f2bf(cur.z * mk.z + prev.z * (1.f - mk.z));
  ok.w = f2bf(cur.w * mk.w + prev.w * (1.f - mk.w));
  ov.x = f2bf(cur.x * mv.x + prev.x * (1.f - mv.x));
  ov.y = f2bf(cur.y * mv.y + prev.y * (1.f - mv.y));
  ov.z = f2bf(cur.z * mv.z + prev.z * (1.f - mv.z));
  ov.w = f2bf(cur.w * mv.w + prev.w * (1.f - mv.w));
  orr.x = f2bf(cur.x * mr.x + prev.x * (1.f - mr.x));
  orr.y = f2bf(cur.y * mr.y + prev.y * (1.f - mr.y));
  orr.z = f2bf(cur.z * mr.z + prev.z * (1.f - mr.z));
  orr.w = f2bf(cur.w * mr.w + prev.w * (1.f - mr.w));
  xk[i] = ok; xv[i] = ov; xr[i] = orr;
}

// ---------------- bf16 NT GEMM: C[M,N] = A[M,K] * B[N,K]^T ----------------
// 256x256 tile, BK=32, 8 waves (2M x 4N), per-wave 128x64. Ring-of-4 LDS
// K-tile slots (128 KiB), stage 3 tiles ahead, counted vmcnt(8) once per
// tile (r1-verified skeleton).
// NEW: m201-template phase shape. MFMA = 16x16x32 (16 MFMA / 262 KFLOP per
// phase); per K-tile two phases (m-half 0, m-half 1), each:
//   [8 or 4 ds_read_b128 (phase's OWN frags) | 2 global_load_lds |
//    (vmcnt on odd phase) | sched_bar | s_barrier | lgkmcnt(0) | sched_bar |
//    setprio(1) 16 MFMA setprio(0) | sched_bar | s_barrier]
// The lgkmcnt(0) placed AFTER the barrier is the point: ds_read latency
// drains during the barrier wait (r2 failed because the wait preceded the
// barrier). Trailing barrier per phase = WAR protection: all waves' reads
// of slot s are lgkm-complete before any wave passes it, and the next
// re-stage of that slot issues only after it.
// Visibility: tile t's A staged phase 2t-6, B at 2t-5; at the vmcnt point
// (phase 2t-1, odd) the loads younger than B(t) are stages of phases
// 2t-4..2t-1 = 4 phases x 2 = 8 -> vmcnt(8) lands tile t before its phase-2t
// reads. Drain: t+3==NT -> vmcnt(4); t+2==NT -> vmcnt(0).
// Ring WAR: STAGE_A((t+3)&3) (= slot of tile t-1) issues after the trailing
// barrier of phase 2t-1, which follows tile t-1's last reads (lgkm'd).
// Frag layouts (m89/m91/m92-verified): A/B lane l -> row=l&15,
// k=(l>>4)*8+j (one b128 per frag); C/D col=lane&15, row=(lane>>4)*4+reg.
// Swizzle (r1 pair, conflict-balanced for 16-row frags): LDS chunk
// c = g ^ ((row>>1)&3); staging applies the inverse on the global source.
// EPI: 0 = fp32; 1 = sigmoid bf16; 2 = bf16.

template <int EPI>
__global__ __launch_bounds__(512, 2) void gemm_bt(
    const unsigned short* __restrict__ A, const unsigned short* __restrict__ B,
    float* __restrict__ Cf, unsigned short* __restrict__ Cb,
    int M, int N, int K) {
  // 4 ring slots x (A 256x32 | B 256x32) bf16 = 4 x 32 KiB = 128 KiB
  __shared__ unsigned short lds[4 * 16384];

  const int tid = threadIdx.x;
  const int wave = tid >> 6;
  const int lane = tid & 63;

  // XCD-aware bijective block swizzle: nwg % 8 == 0 (256 blocks).
  const int nwg = (int)gridDim.x;
  const int q = nwg >> 3;
  const int wg = (blockIdx.x & 7) * q + (blockIdx.x >> 3);
  const int GM = M >> 8;
  const int bm = (wg % GM) * 256;
  const int bn = (wg / GM) * 256;

  const int wm = (wave >> 2) * 128;    // wave's 128x64 sub-tile
  const int wn = (wave & 3) * 64;
  const int l15 = lane & 15;           // frag row within 16
  const int lg = lane >> 4;            // k-group (0..3)

  f32x4 acc[8][4] = {};                // 8 m-frags x 4 n-frags x 4 f32

  // ---- staging addresses (per thread: 4 x 16B per K-tile; r1-verified) ----
  const int srow = tid >> 2;
  const int sg = ((tid & 3) ^ ((srow >> 1) & 3)) * 8;
  const unsigned short* gA0 = A + (long long)(bm + srow) * K + sg;
  const unsigned short* gA1 = A + (long long)(bm + 128 + srow) * K + sg;
  const unsigned short* gB0 = B + (long long)(bn + srow) * K + sg;
  const unsigned short* gB1 = B + (long long)(bn + 128 + srow) * K + sg;

#define STAGE_A(sl)                                            \
  {                                                            \
    unsigned short* dst = lds + (sl) * 16384 + wave * 512;     \
    gload_lds16(gA0, dst);                                     \
    gload_lds16(gA1, dst + 4096);                              \
    gA0 += 32; gA1 += 32;                                      \
  }
#define STAGE_B(sl)                                            \
  {                                                            \
    unsigned short* dst = lds + (sl) * 16384 + wave * 512;     \
    gload_lds16(gB0, dst + 8192);                              \
    gload_lds16(gB1, dst + 12288);                             \
    gB0 += 32; gB1 += 32;                                      \
  }

  // ---- fragment LDS offsets (shorts; loop-invariant) ----
  // row R, k-group g -> R*32 + ((g ^ ((R>>1)&3)) * 8)
  int offA[8], offB[4];
#pragma unroll
  for (int mi = 0; mi < 8; ++mi) {
    int R = wm + mi * 16 + l15;
    offA[mi] = R * 32 + ((lg ^ ((R >> 1) & 3)) * 8);
  }
#pragma unroll
  for (int ni = 0; ni < 4; ++ni) {
    int R = wn + ni * 16 + l15;
    offB[ni] = 8192 + R * 32 + ((lg ^ ((R >> 1) & 3)) * 8);
  }

  const int NT = K >> 5;   // K/32 (= 64 here; >= 4 required)

  // ---- prologue: stage tiles 0,1,2; tile 0 landed (8 in flight) ----
  STAGE_A(0); STAGE_B(0);
  STAGE_A(1); STAGE_B(1);
  STAGE_A(2); STAGE_B(2);
  asm volatile("s_waitcnt vmcnt(8)" ::: "memory");
  __builtin_amdgcn_sched_barrier(0);
  __builtin_amdgcn_s_barrier();

  for (int t = 0; t < NT; ++t) {
    const unsigned short* sb = lds + (t & 3) * 16384;
    const bool pf = (t + 3 < NT);

    // ======== phase 0: m-half 0 ========
    s16x8 a[4], b[4];
#pragma unroll
    for (int mi = 0; mi < 4; ++mi) a[mi] = *(const s16x8*)(sb + offA[mi]);
#pragma unroll
    for (int ni = 0; ni < 4; ++ni) b[ni] = *(const s16x8*)(sb + offB[ni]);
    if (pf) STAGE_A((t + 3) & 3);
    __builtin_amdgcn_sched_barrier(0);
    __builtin_amdgcn_s_barrier();
    asm volatile("s_waitcnt lgkmcnt(0)" ::: "memory");
    __builtin_amdgcn_sched_barrier(0);
    __builtin_amdgcn_s_setprio(1);
#pragma unroll
    for (int mi = 0; mi < 4; ++mi)
#pragma unroll
      for (int ni = 0; ni < 4; ++ni)
        acc[mi][ni] = __builtin_amdgcn_mfma_f32_16x16x32_bf16(
            a[mi], b[ni], acc[mi][ni], 0, 0, 0);
    __builtin_amdgcn_s_setprio(0);
    __builtin_amdgcn_sched_barrier(0);
    __builtin_amdgcn_s_barrier();

    // ======== phase 1: m-half 1 ========
    s16x8 a2[4];
#pragma unroll
    for (int mi = 0; mi < 4; ++mi) a2[mi] = *(const s16x8*)(sb + offA[4 + mi]);
    if (pf) STAGE_B((t + 3) & 3);
    if (pf) {
      asm volatile("s_waitcnt vmcnt(8)" ::: "memory");   // tile t+1 landed
    } else if (t + 3 == NT) {
      asm volatile("s_waitcnt vmcnt(4)" ::: "memory");   // drain
    } else if (t + 2 == NT) {
      asm volatile("s_waitcnt vmcnt(0)" ::: "memory");   // drain: last tile
    }
    __builtin_amdgcn_sched_barrier(0);
    __builtin_amdgcn_s_barrier();
    asm volatile("s_waitcnt lgkmcnt(0)" ::: "memory");
    __builtin_amdgcn_sched_barrier(0);
    __builtin_amdgcn_s_setprio(1);
#pragma unroll
    for (int mi = 0; mi < 4; ++mi)
#pragma unroll
      for (int ni = 0; ni < 4; ++ni)
        acc[4 + mi][ni] = __builtin_amdgcn_mfma_f32_16x16x32_bf16(
            a2[mi], b[ni], acc[4 + mi][ni], 0, 0, 0);
    __builtin_amdgcn_s_setprio(0);
    __builtin_amdgcn_sched_barrier(0);
    __builtin_amdgcn_s_barrier();
  }
#undef STAGE_A
#undef STAGE_B

  // epilogue: 16x16 C/D layout col = lane&15, row = (lane>>4)*4 + reg
#pragma unroll
  for (int mi = 0; mi < 8; ++mi)
#pragma unroll
    for (int ni = 0; ni < 4; ++ni)
#pragma unroll
      for (int r = 0; r < 4; ++r) {
        int row = bm + wm + mi * 16 + lg * 4 + r;
        int col = bn + wn + ni * 16 + l15;
        float v = acc[mi][ni][r];
        long long idx = (long long)row * N + col;
        if (EPI == 0) {
          Cf[idx] = v;
        } else if (EPI == 1) {
          float s = 1.f / (1.f + __expf(-v));
          Cb[idx] = f2bf(s);
        } else {
          Cb[idx] = f2bf(v);
        }
      }
}

// ---------------- chunked WKV scan (k now bf16) ----------------

#define NEG_INF_F (-1e38f)

__global__ void scan_phase1(const unsigned short* __restrict__ kb,
                            const unsigned short* __restrict__ vb,
                            const float* __restrict__ td,
                            float* __restrict__ locN, float* __restrict__ locD,
                            float* __restrict__ locM,
                            int S, int D, int C, int L) {
  int t = blockIdx.x * blockDim.x + threadIdx.x;  // over B*C*D
  int d = t % D;
  int c = (t / D) % C;
  int b = t / (D * C);
  float w = -__expf(td[d]);
  float num = 0.f, den = 0.f, m = NEG_INF_F;
  long long base = ((long long)(b * S + c * L)) * D + d;
  for (int i = 0; i < L; ++i) {
    float kk = bf2f(kb[base]);
    float vv = bf2f(vb[base]);
    base += D;
    float mn = fmaxf(m + w, kk);
    float e1 = __expf(m + w - mn);
    float e2 = __expf(kk - mn);
    num = e1 * num + e2 * vv;
    den = e1 * den + e2;
    m = mn;
  }
  int o = (b * C + c) * D + d;
  locN[o] = num; locD[o] = den; locM[o] = m;
}

__global__ void scan_phase2(const float* __restrict__ td,
                            const float* __restrict__ locN, const float* __restrict__ locD,
                            const float* __restrict__ locM,
                            float* __restrict__ inN, float* __restrict__ inD,
                            float* __restrict__ inM,
                            int Bc, int D, int C, int L) {
  int t = blockIdx.x * blockDim.x + threadIdx.x;  // over B*D
  if (t >= Bc * D) return;
  int d = t % D, b = t / D;
  float w = -__expf(td[d]);
  float Lw = (float)L * w;
  float num = 0.f, den = 0.f, m = NEG_INF_F;
  for (int c = 0; c < C; ++c) {
    int o = (b * C + c) * D + d;
    inN[o] = num; inD[o] = den; inM[o] = m;
    float sm = m + Lw;                 // decay incoming state over whole chunk
    float lm = locM[o];
    float m2 = fmaxf(sm, lm);
    float e1 = __expf(sm - m2);
    float e2 = __expf(lm - m2);
    num = e1 * num + e2 * locN[o];
    den = e1 * den + e2 * locD[o];
    m = m2;
  }
}

__global__ void scan_phase3(const unsigned short* __restrict__ kb,
                            const unsigned short* __restrict__ vb,
                            const unsigned short* __restrict__ rb,
                            const float* __restrict__ td, const float* __restrict__ tfirst,
                            const float* __restrict__ inN, const float* __restrict__ inD,
                            const float* __restrict__ inM,
                            unsigned short* __restrict__ rr,
                            int S, int D, int C, int L) {
  int t = blockIdx.x * blockDim.x + threadIdx.x;  // over B*C*D
  int d = t % D;
  int c = (t / D) % C;
  int b = t / (D * C);
  float w = -__expf(td[d]);
  float tfd = tfirst[d];
  int o = (b * C + c) * D + d;
  float num = inN[o], den = inD[o], m = inM[o];
  long long base = ((long long)(b * S + c * L)) * D + d;
  for (int i = 0; i < L; ++i) {
    float kk = bf2f(kb[base]);
    float vv = bf2f(vb[base]);
    float rv = bf2f(rb[base]);
    float ktf = kk + tfd;
    float mo = fmaxf(m, ktf);
    float e1 = __expf(m - mo);
    float e2 = __expf(ktf - mo);
    float out = (e1 * num + e2 * vv) / (e1 * den + e2);
    rr[base] = f2bf(out * rv);
    float mn = fmaxf(m + w, kk);
    e1 = __expf(m + w - mn);
    e2 = __expf(kk - mn);
    num = e1 * num + e2 * vv;
    den = e1 * den + e2;
    m = mn;
    base += D;
  }
}

// ---------------- launch ----------------

extern "C" void kernel_launch(void* const* d_in, const int* in_sizes, int n_in,
                              void* d_out, int out_size, void* d_ws, size_t ws_size,
                              hipStream_t stream) {
  const float* hidden = (const float*)d_in[0];
  const float* td  = (const float*)d_in[1];
  const float* tfi = (const float*)d_in[2];
  const float* tmk = (const float*)d_in[3];
  const float* tmv = (const float*)d_in[4];
  const float* tmr = (const float*)d_in[5];
  const float* Wk  = (const float*)d_in[6];
  const float* Wv  = (const float*)d_in[7];
  const float* Wr  = (const float*)d_in[8];
  const float* Wo  = (const float*)d_in[9];
  float* out = (float*)d_out;

  const int H = in_sizes[1];                 // 2048
  const int D = H;
  const long long BS = (long long)in_sizes[0] / H;  // 8192 = B*S
  const int S = 2048;
  const int B = (int)(BS / S);               // 4
  const int C = 32, L = S / C;               // 32 chunks of 64

  // workspace layout (110 MiB, proven safe):
  //   W_b [0,8) | X [8,40) | Y [40,72) | Z [72,104) | states [104,110)
  char* ws = (char*)d_ws;
  const size_t MB = 1u << 20;
  unsigned short* W_b = (unsigned short*)(ws + 0 * MB);
  unsigned short* X   = (unsigned short*)(ws + 8 * MB);
  unsigned short* Y   = (unsigned short*)(ws + 40 * MB);
  unsigned short* Z   = (unsigned short*)(ws + 72 * MB);
  float* locN         = (float*)(ws + 104 * MB);
  float* locD         = (float*)(ws + 105 * MB);
  float* locM         = (float*)(ws + 106 * MB);
  float* inN          = (float*)(ws + 107 * MB);
  float* inD          = (float*)(ws + 108 * MB);
  float* inM          = (float*)(ws + 109 * MB);
  unsigned short* kb  = (unsigned short*)out;   // bf16 k scratch in d_out

  int n4w = H * H / 4;
  int cbk = (n4w + 255) / 256;
  long long total4 = BS * H / 4;
  int pbk = (int)((total4 + 255) / 256);
  int nwg = (int)((BS / 256) * (D / 256));   // 32 * 8 = 256 blocks, 1/CU

  // fused time-shift mix (one pass over hidden)
  prep_mix3<<<pbk, 256, 0, stream>>>((const float4*)hidden,
                                     (const float4*)tmk, (const float4*)tmv, (const float4*)tmr,
                                     (ushort4*)X, (ushort4*)Y, (ushort4*)Z, S, H / 4, total4);

  // k = xk @ Wk^T  (bf16 -> d_out scratch)
  conv_bf16<<<cbk, 256, 0, stream>>>((const float4*)Wk, (ushort4*)W_b, n4w);
  gemm_bt<2><<<nwg, 512, 0, stream>>>(X, W_b, nullptr, kb, (int)BS, D, H);

  // v = xv @ Wv^T  (bf16 -> X)
  conv_bf16<<<cbk, 256, 0, stream>>>((const float4*)Wv, (ushort4*)W_b, n4w);
  gemm_bt<2><<<nwg, 512, 0, stream>>>(Y, W_b, nullptr, X, (int)BS, D, H);

  // r = sigmoid(xr @ Wr^T)  (bf16 -> Y)
  conv_bf16<<<cbk, 256, 0, stream>>>((const float4*)Wr, (ushort4*)W_b, n4w);
  gemm_bt<1><<<nwg, 512, 0, stream>>>(Z, W_b, nullptr, Y, (int)BS, D, H);

  // chunked WKV scan, fused r * rwkv -> Z (bf16)
  int nscan = B * C * D;
  scan_phase1<<<nscan / 256, 256, 0, stream>>>(kb, X, td, locN, locD, locM, S, D, C, L);
  scan_phase2<<<(B * D + 255) / 256, 256, 0, stream>>>(td, locN, locD, locM, inN, inD, inM, B, D, C, L);
  scan_phase3<<<nscan / 256, 256, 0, stream>>>(kb, X, Y, td, tfi, inN, inD, inM, Z, S, D, C, L);

  // out = (r * rwkv) @ Wo^T  (fp32 -> d_out; kb dead now)
  conv_bf16<<<cbk, 256, 0, stream>>>((const float4*)Wo, (ushort4*)W_b, n4w);
  gemm_bt<0><<<nwg, 512, 0, stream>>>(Z, W_b, out, nullptr, (int)BS, H, D);
}